// Round 1
// 181.926 us; speedup vs baseline: 1.1480x; 1.1480x over previous
//
#include <hip/hip_runtime.h>
#include <hip/hip_fp16.h>
#include <math.h>

#define N_NODES 100000
#define N_EDGES 3200000
#define DIM 16
#define NSZ (N_NODES * DIM)

#define NPB 128         // nodes per bucket (bucket = col>>7, cl = col&127)
#define NBUCK 782       // ceil(100000/128)
#define NBLK 512        // partition blocks
#define EPB 6250        // edges per partition block: 512*6250 = 3.2M exactly
#define CAP 4864        // aggregate LDS edge capacity (mean 4096; 40.4KB -> 4 blocks/CU)
#define PRK 10          // ceil(CAP/512) register-carried packed entries per thread

// packed entry: [63:47]=col(17) [46:30]=row(17) [29:0]=w bits>>2
typedef float nvec4 __attribute__((ext_vector_type(4)));

// ---- 1) fused: f32->f16 convert + per-block bucket histogram -> tbl[bucket][blk]
__global__ __launch_bounds__(512)
void hist_table(const float* __restrict__ state, __half* __restrict__ hs,
                const int* __restrict__ col, unsigned* __restrict__ tbl) {
    __shared__ int hcnt[NBUCK];
    int t = threadIdx.x, blk = blockIdx.x;
    for (int j = t; j < NBUCK; j += 512) hcnt[j] = 0;
    for (int i = blk * 512 + t; i < NSZ / 4; i += NBLK * 512) {
        nvec4 v = __builtin_nontemporal_load(&((const nvec4*)state)[i]);
        union { __half2 h[2]; float2 f; } u;
        u.h[0] = __floats2half2_rn(v.x, v.y);
        u.h[1] = __floats2half2_rn(v.z, v.w);
        ((float2*)hs)[i] = u.f;
    }
    __syncthreads();
    int e0 = blk * EPB;
    for (int i = t; i < EPB; i += 512)
        atomicAdd(&hcnt[col[e0 + i] >> 7], 1);
    __syncthreads();
    for (int j = t; j < NBUCK; j += 512)
        tbl[(size_t)j * NBLK + blk] = (unsigned)hcnt[j];
}

// ---- 2a) per-bucket totals ----
__global__ __launch_bounds__(256)
void col_reduce(const unsigned* __restrict__ tbl, int* __restrict__ totals) {
    __shared__ int s[256];
    int b = blockIdx.x, t = threadIdx.x;
    int v = (int)tbl[(size_t)b * NBLK + t] + (int)tbl[(size_t)b * NBLK + 256 + t];
    s[t] = v;
    __syncthreads();
    for (int d = 128; d > 0; d >>= 1) {
        if (t < d) s[t] += s[t + d];
        __syncthreads();
    }
    if (t == 0) totals[b] = s[0];
}

// ---- 2b) exclusive scan of 782 totals -> off[783] ----
__global__ __launch_bounds__(1024)
void scan_off(const int* __restrict__ totals, int* __restrict__ off) {
    __shared__ int s[1024];
    int t = threadIdx.x;
    int v = (t < NBUCK) ? totals[t] : 0;
    s[t] = v;
    __syncthreads();
    for (int d = 1; d < 1024; d <<= 1) {
        int u = (t >= d) ? s[t - d] : 0;
        __syncthreads();
        s[t] += u;
        __syncthreads();
    }
    if (t < NBUCK) off[t + 1] = s[t];
    if (t == 0) off[0] = 0;
}

// ---- 2c) tbl counts -> global write bases, in place ----
__global__ __launch_bounds__(512)
void base_scan(unsigned* __restrict__ tbl, const int* __restrict__ off) {
    __shared__ int s[512];
    int b = blockIdx.x, t = threadIdx.x;
    int v = (int)tbl[(size_t)b * NBLK + t];
    s[t] = v;
    __syncthreads();
    for (int d = 1; d < 512; d <<= 1) {
        int u = (t >= d) ? s[t - d] : 0;
        __syncthreads();
        s[t] += u;
        __syncthreads();
    }
    tbl[(size_t)b * NBLK + t] = (unsigned)(off[b] + s[t] - v);   // exclusive
}

// ---- 3) sort_write: counts DERIVED from tbl (no re-histogram), LDS scatter,
//         dense sweep with bucket decoded from the entry (no binary search) ----
__global__ __launch_bounds__(512)
void sort_write(const int* __restrict__ row, const int* __restrict__ col,
                const float* __restrict__ w, const unsigned* __restrict__ tbl,
                const int* __restrict__ off,
                unsigned long long* __restrict__ packed) {
    __shared__ unsigned long long sbuf[EPB];   // 50,000 B
    __shared__ int sc[1024];                   // scan scratch -> lstart
    __shared__ int cur[NBUCK];                 // counts -> scatter cursor
    __shared__ int gbase[NBUCK];
    int t = threadIdx.x, blk = blockIdx.x;
    int e0 = blk * EPB;

    for (int j = t; j < NBUCK; j += 512) {     // bases + derived counts
        int b0 = (int)tbl[(size_t)j * NBLK + blk];
        int b1 = (blk == NBLK - 1) ? off[j + 1]
                                   : (int)tbl[(size_t)j * NBLK + blk + 1];
        gbase[j] = b0;
        cur[j] = b1 - b0;                      // count
    }
    __syncthreads();
    sc[t]       = (t < NBUCK)       ? cur[t]       : 0;
    sc[t + 512] = (t + 512 < NBUCK) ? cur[t + 512] : 0;
    __syncthreads();
    for (int d = 1; d < 1024; d <<= 1) {
        int u1 = (t >= d) ? sc[t - d] : 0;
        int u2 = sc[t + 512 - d];              // t+512 >= d always
        __syncthreads();
        sc[t] += u1;
        sc[t + 512] += u2;
        __syncthreads();
    }
    for (int j = t; j < NBUCK; j += 512) {     // inclusive -> exclusive
        int ex = sc[j] - cur[j];
        sc[j] = ex;                            // lstart (persist for sweep)
        cur[j] = ex;                           // scatter cursor
    }
    __syncthreads();
    for (int i = t; i < EPB; i += 512) {       // single edge pass: LDS scatter
        int e = e0 + i;
        int c = col[e];
        int pos = atomicAdd(&cur[c >> 7], 1);
        sbuf[pos] = ((unsigned long long)(unsigned)c << 47)
                  | ((unsigned long long)(unsigned)row[e] << 30)
                  | (unsigned long long)(__float_as_uint(w[e]) >> 2);
    }
    __syncthreads();
    for (int i = t; i < EPB; i += 512) {       // dense sweep; bucket from entry
        unsigned long long pv = sbuf[i];
        int b = (int)(pv >> 54);               // col>>7
        __builtin_nontemporal_store(pv, &packed[gbase[b] + (i - sc[b])]);
    }
}

// one edge's contribution to 4 dims (lane q of a 4-lane node group)
__device__ inline float4 edge_acc(float4 a, const float4 xx,
                                  unsigned long long p, float2 hbits) {
    union { float2 f; __half2 h[2]; } u; u.f = hbits;
    float2 lo = __half22float2(u.h[0]);
    float2 hi = __half22float2(u.h[1]);
    float we = __uint_as_float(((unsigned)p & 0x3FFFFFFFu) << 2);
    a.x += __sinf(lo.x - xx.x) * we;
    a.y += __sinf(lo.y - xx.y) * we;
    a.z += __sinf(hi.x - xx.z) * we;
    a.w += __sinf(hi.y - xx.w) * we;
    return a;
}

// ---- 4) per-bucket: coalesced read (register-carried), in-LDS cl-sort,
//         owner-computes: 4 lanes/node, one round, unroll-4 edge sweep ----
__global__ __launch_bounds__(512)
void bucket_sort_aggregate(const float* __restrict__ state,
                           const __half2* __restrict__ hs2,
                           const int* __restrict__ off,
                           const unsigned long long* __restrict__ packed,
                           float* __restrict__ out) {
    __shared__ unsigned long long sbuf[CAP];       // 38,912 B cl-sorted edges
    __shared__ int s_cnt[NPB], s_start[NPB], s_cur[NPB];
    int b = blockIdx.x, t = threadIdx.x;
    int g = t >> 2, q = t & 3;                     // 128 groups x 4 lanes
    int beg = off[b], end = off[b + 1];

    int n = b * NPB + g;
    bool valid = (n < N_NODES);
    float4 xx = valid ? ((const float4*)state)[n * 4 + q]
                      : make_float4(0.f, 0.f, 0.f, 0.f);
    float4 acc = make_float4(0.f, 0.f, 0.f, 0.f);
    const float2* hsf2 = (const float2*)hs2;

    for (int tbeg = beg; tbeg < end; tbeg += CAP) {
        int tend = tbeg + CAP; if (tend > end) tend = end;
        if (t < NPB) s_cnt[t] = 0;
        __syncthreads();

        // phase 1: coalesced read, carried in registers; LDS cl-histogram
        unsigned long long pr[PRK];
        #pragma unroll
        for (int k = 0; k < PRK; ++k) {
            int e = tbeg + t + k * 512;
            if (e < tend) {
                pr[k] = __builtin_nontemporal_load(&packed[e]);
                atomicAdd(&s_cnt[(unsigned)(pr[k] >> 47) & 127u], 1);
            }
        }
        __syncthreads();

        // phase 2: exclusive scan of 128 counts
        if (t < NPB) s_start[t] = s_cnt[t];
        __syncthreads();
        for (int d = 1; d < NPB; d <<= 1) {
            int u = 0;
            if (t < NPB && t >= d) u = s_start[t - d];
            __syncthreads();
            if (t < NPB) s_start[t] += u;
            __syncthreads();
        }
        if (t < NPB) {
            int ex = s_start[t] - s_cnt[t];
            s_start[t] = ex;
            s_cur[t] = ex;
        }
        __syncthreads();

        // phase 3: scatter from registers (no second global read)
        #pragma unroll
        for (int k = 0; k < PRK; ++k) {
            int e = tbeg + t + k * 512;
            if (e < tend) {
                int cl = (int)((pr[k] >> 47) & 127u);
                int pos = atomicAdd(&s_cur[cl], 1);
                sbuf[pos] = pr[k];
            }
        }
        __syncthreads();

        // phase 4: owner-computes sweep, unroll-4 for ILP on the two
        // latency chains (ds_read_b64 ~120cy, L2 gather ~200cy)
        {
            int es = s_start[g], ee = s_cur[g];
            float4 a = acc;
            int e = es;
            for (; e + 4 <= ee; e += 4) {
                unsigned long long p0 = sbuf[e + 0];
                unsigned long long p1 = sbuf[e + 1];
                unsigned long long p2 = sbuf[e + 2];
                unsigned long long p3 = sbuf[e + 3];
                float2 h0 = hsf2[(unsigned)((p0 >> 30) & 0x1FFFFu) * 4u + q];
                float2 h1 = hsf2[(unsigned)((p1 >> 30) & 0x1FFFFu) * 4u + q];
                float2 h2 = hsf2[(unsigned)((p2 >> 30) & 0x1FFFFu) * 4u + q];
                float2 h3 = hsf2[(unsigned)((p3 >> 30) & 0x1FFFFu) * 4u + q];
                a = edge_acc(a, xx, p0, h0);
                a = edge_acc(a, xx, p1, h1);
                a = edge_acc(a, xx, p2, h2);
                a = edge_acc(a, xx, p3, h3);
            }
            for (; e < ee; ++e) {
                unsigned long long p0 = sbuf[e];
                float2 h0 = hsf2[(unsigned)((p0 >> 30) & 0x1FFFFu) * 4u + q];
                a = edge_acc(a, xx, p0, h0);
            }
            acc = a;
        }
        __syncthreads();
    }

    if (valid) {
        float4 th = make_float4(tanhf(acc.x), tanhf(acc.y),
                                tanhf(acc.z), tanhf(acc.w));
        int gdx = n * 4 + q;
        ((float4*)(out + 0 * (size_t)NSZ))[gdx] =
            make_float4(th.x - xx.x, th.y - xx.y, th.z - xx.z, th.w - xx.w);
        ((float4*)(out + 1 * (size_t)NSZ))[gdx] = xx;
        ((float4*)(out + 2 * (size_t)NSZ))[gdx] =
            make_float4(-xx.x, -xx.y, -xx.z, -xx.w);
        ((float4*)(out + 3 * (size_t)NSZ))[gdx] = acc;
        ((float4*)(out + 4 * (size_t)NSZ))[gdx] = th;
    }
}

// ---- fallback (tiny ws): round-1 atomic path ----
__global__ __launch_bounds__(256)
void edge_kernel(const float* __restrict__ state, const int* __restrict__ row,
                 const int* __restrict__ col, const float* __restrict__ w,
                 float* __restrict__ agg) {
    int idx = blockIdx.x * blockDim.x + threadIdx.x;
    if (idx >= N_EDGES * 4) return;
    int e = idx >> 2, qq = idx & 3;
    int r = row[e], c = col[e];
    float we = w[e];
    const float4 xr = ((const float4*)state)[r * 4 + qq];
    const float4 xcv = ((const float4*)state)[c * 4 + qq];
    float* dst = agg + c * DIM + qq * 4;
    atomicAdd(dst + 0, sinf(xr.x - xcv.x) * we);
    atomicAdd(dst + 1, sinf(xr.y - xcv.y) * we);
    atomicAdd(dst + 2, sinf(xr.z - xcv.z) * we);
    atomicAdd(dst + 3, sinf(xr.w - xcv.w) * we);
}

__global__ __launch_bounds__(256)
void node_kernel(const float* __restrict__ state, const float* __restrict__ agg,
                 float* __restrict__ out) {
    int idx = blockIdx.x * blockDim.x + threadIdx.x;
    if (idx >= N_NODES * 4) return;
    float4 x = ((const float4*)state)[idx];
    float4 a = ((const float4*)agg)[idx];
    float4 tv = make_float4(tanhf(a.x), tanhf(a.y), tanhf(a.z), tanhf(a.w));
    ((float4*)(out + 0 * NSZ))[idx] = make_float4(tv.x - x.x, tv.y - x.y,
                                                  tv.z - x.z, tv.w - x.w);
    ((float4*)(out + 1 * NSZ))[idx] = x;
    ((float4*)(out + 2 * NSZ))[idx] = make_float4(-x.x, -x.y, -x.z, -x.w);
    ((float4*)(out + 4 * NSZ))[idx] = tv;
}

extern "C" void kernel_launch(void* const* d_in, const int* in_sizes, int n_in,
                              void* d_out, int out_size, void* d_ws, size_t ws_size,
                              hipStream_t stream) {
    const float* state = (const float*)d_in[0];
    const int*   row   = (const int*)d_in[1];
    const int*   col   = (const int*)d_in[2];
    const float* w     = (const float*)d_in[3];
    float* out = (float*)d_out;

    // ws: packed | hs | tbl | totals | off  (every byte written before read)
    size_t packed_off = 0;
    size_t half_off   = packed_off + (size_t)N_EDGES * 8;          // 25.6MB
    size_t tbl_off    = half_off + (size_t)NSZ * 2;                // +3.2MB
    size_t tot_off    = tbl_off + (size_t)NBUCK * NBLK * 4;        // +1.6MB
    size_t off_off    = tot_off + (size_t)NBUCK * 4;
    size_t needed     = off_off + (size_t)(NBUCK + 1) * 4;

    if (ws_size >= needed) {
        unsigned long long* packed =
            (unsigned long long*)((char*)d_ws + packed_off);
        __half* hs    = (__half*)((char*)d_ws + half_off);
        unsigned* tbl = (unsigned*)((char*)d_ws + tbl_off);
        int* totals   = (int*)((char*)d_ws + tot_off);
        int* off      = (int*)((char*)d_ws + off_off);

        hist_table<<<NBLK, 512, 0, stream>>>(state, hs, col, tbl);
        col_reduce<<<NBUCK, 256, 0, stream>>>(tbl, totals);
        scan_off<<<1, 1024, 0, stream>>>(totals, off);
        base_scan<<<NBUCK, 512, 0, stream>>>(tbl, off);
        sort_write<<<NBLK, 512, 0, stream>>>(row, col, w, tbl, off, packed);
        bucket_sort_aggregate<<<NBUCK, 512, 0, stream>>>(
            state, (const __half2*)hs, off, packed, out);
    } else {
        float* agg = out + 3 * NSZ;
        (void)hipMemsetAsync(agg, 0, NSZ * sizeof(float), stream);
        edge_kernel<<<(N_EDGES * 4 + 255) / 256, 256, 0, stream>>>(
            state, row, col, w, agg);
        node_kernel<<<(N_NODES * 4 + 255) / 256, 256, 0, stream>>>(
            state, agg, out);
    }
}